// Round 14
// baseline (92.647 us; speedup 1.0000x reference)
//
#include <hip/hip_runtime.h>
#include <hip/hip_bf16.h>

#define V 17
#define C_DIM 256
#define TV 1088        // T*V
#define CTV 278528     // C*T*V

typedef __attribute__((ext_vector_type(8))) short short8;
typedef __attribute__((ext_vector_type(4))) short svec4;
typedef __attribute__((ext_vector_type(4))) float f32x4;

static __device__ inline short f2bfs(float f) {
    union { __hip_bfloat16 b; short s; } u;
    u.b = __float2bfloat16(f);
    return u.s;
}
static __device__ inline float bfs2f(short s) {
    union { float f; unsigned u; } q;
    q.u = ((unsigned)(unsigned short)s) << 16;
    return q.f;
}

// ws layout (bytes):
//   0      : wtb (65536 bf16)  blocked W^T: wtb[(kc*256+d)*32+kk] = W[kc*32+kk][d]
//   131072 : g   (4352 f32)    tanh(fm)+1
//   148480 : scl (4352 f32)    [u][d] = gamma[v,d]/sqrt(var[v,d]+eps),  v=(u+d)%17
//   165888 : ofs (4352 f32)    [u][d] = (lin_b[d]-mean[v,d])*scl+beta[v,d]
//   183296 : gnv (4352 f32)    [u][d] = 1/g[u][d]
__global__ __launch_bounds__(256) void prep_kernel(
    const float* __restrict__ fm, const float* __restrict__ W,
    const float* __restrict__ lb, const float* __restrict__ gamma,
    const float* __restrict__ beta, const float* __restrict__ mean,
    const float* __restrict__ var,
    __hip_bfloat16* __restrict__ wtb, float* __restrict__ g,
    float* __restrict__ scl, float* __restrict__ ofs, float* __restrict__ gnv)
{
    int i = blockIdx.x * 256 + threadIdx.x;   // 65536 threads
    int c = i >> 8, d = i & 255;
    float w = W[i];
    wtb[((c >> 5) * 256 + d) * 32 + (c & 31)] = __float2bfloat16(w);
    if (i < V * C_DIM) {
        float gv = tanhf(fm[i]) + 1.0f;
        g[i]   = gv;
        gnv[i] = 1.0f / gv;
        int u = i >> 8;                        // GEMM-row joint
        int v = u + d; v %= V;                 // OUTPUT joint = (u+d) mod 17
        int k = v * C_DIM + d;                 // BN parameter index
        float sc = gamma[k] * rsqrtf(var[k] + 1e-5f);
        scl[i] = sc;
        ofs[i] = (lb[d] - mean[k]) * sc + beta[k];
    }
}

// ---- staging task (single t-row): gather 8 channels for row u, gate, cast,
//      one short8 LDS write into the XOR-swizzled A-tile.
static __device__ __forceinline__ void stage_task(
    int t, short* As, const float* __restrict__ xplane, const float* __restrict__ g)
{
    int kkc = t / 17;                  // 0..31 (16B slot index)
    int u   = t - kkc * 17;            // 0..16 (GEMM-row joint)
    int c0  = kkc * 8;
    const float* gp = g + u * C_DIM + c0;
    float4 g0 = *(const float4*)gp;
    float4 g1 = *(const float4*)(gp + 4);
    float gg[8] = {g0.x, g0.y, g0.z, g0.w, g1.x, g1.y, g1.z, g1.w};
    int mm = (u + c0) % V;
    float xv[8];
    #pragma unroll
    for (int i = 0; i < 8; ++i) {
        xv[i] = xplane[(c0 + i) * TV + mm];
        mm = (mm == V - 1) ? 0 : mm + 1;
    }
    short av[8];
    #pragma unroll
    for (int i = 0; i < 8; ++i) av[i] = f2bfs(xv[i] * gg[i]);
    *(short8*)(As + u * 256 + ((kkc ^ (u & 7)) << 3)) =
        (short8){av[0], av[1], av[2], av[3], av[4], av[5], av[6], av[7]};
}

// Block: ONE t-row (17 GEMM rows, padded to 32), all 256 d. 256 thr / 4 waves;
// wave wv owns d in [wv*64, wv*64+64) -> acc[4][2] = 32 AGPR. A-tile LDS
// [32][256] bf16 = 16 KB, XOR swizzle. launch_bounds(256,5): <=102 unified
// regs (32 acc + <=70 arch) -> 5 waves/SIMD, 5 blocks/CU.
// MFMA swapped operands (l15 = GEMM row pos, lq*4+rg = d); direct epilogue
// applies the output shift v=(pos+d)%17; residual recovered from As*(1/g).
__global__ __launch_bounds__(256, 5) void shiftgcn_kernel(
    const float* __restrict__ x0, const __hip_bfloat16* __restrict__ wtb,
    const float* __restrict__ g, const float* __restrict__ scl,
    const float* __restrict__ ofs, const float* __restrict__ gnv,
    float* __restrict__ out)
{
    __shared__ __align__(16) short As[32 * 256];   // 16384 B

    const int tid  = threadIdx.x;
    const int lane = tid & 63;
    const int wv   = tid >> 6;                // 0..3
    const int l15  = lane & 15;
    const int lq   = lane >> 4;

    // T1: 4096 wg = 8 XCD x 512 contiguous tiles (bijective)
    const int wg = (blockIdx.x & 7) * 512 + (blockIdx.x >> 3);
    const int n  = wg >> 6;
    const int tr = wg & 63;                   // t-row within the sample
    const float* xplane = x0 + n * CTV + tr * V;   // + c*TV + joint

    // zero pad rows 17..31 (15 rows * 256 halves = 480 short8)
    for (int j = tid; j < 480; j += 256)
        ((short8*)(As + 17 * 256))[j] = (short8)0;

    // ---- Phase 1: stage all K. 544 tasks = 2 full rounds + 32-thread tail.
    stage_task(tid,       As, xplane, g);
    stage_task(256 + tid, As, xplane, g);
    if (tid < 32) stage_task(512 + tid, As, xplane, g);
    __syncthreads();   // the ONLY barrier

    // ---- Phase 2: MFMA, swapped operands. Wave wv owns d in [wv*64,+64).
    f32x4 acc[4][2];   // [dTile][posTile]
    #pragma unroll
    for (int ni = 0; ni < 4; ++ni)
        #pragma unroll
        for (int mi = 0; mi < 2; ++mi)
            acc[ni][mi] = (f32x4){0.f, 0.f, 0.f, 0.f};

    #pragma unroll
    for (int kc = 0; kc < 8; ++kc) {
        short8 wfr[4];
        #pragma unroll
        for (int ni = 0; ni < 4; ++ni)
            wfr[ni] = *(const short8*)(wtb +
                ((kc * 256 + wv * 64 + ni * 16 + l15) << 5) + lq * 8);
        short8 a[2];
        #pragma unroll
        for (int mi = 0; mi < 2; ++mi) {
            int row = mi * 16 + l15;
            a[mi] = *(const short8*)(As + row * 256 +
                ((((kc << 2) | lq) ^ (row & 7)) << 3));
        }
        #pragma unroll
        for (int ni = 0; ni < 4; ++ni)
            #pragma unroll
            for (int mi = 0; mi < 2; ++mi)
                acc[ni][mi] = __builtin_amdgcn_mfma_f32_16x16x32_bf16(
                    wfr[ni], a[mi], acc[ni][mi], 0, 0, 0);
    }

    // ---- Phase 3: direct epilogue. pos = mi*16+l15 (= GEMM-row joint, tl=0),
    //      d = wv*64 + ni*16 + lq*4 + rg, output joint vv = (pos+d)%17.
    #pragma unroll
    for (int ni = 0; ni < 4; ++ni) {
        const int D0 = wv * 64 + ni * 16 + lq * 4;
        const int dm = D0 % V;
        #pragma unroll
        for (int mi = 0; mi < 2; ++mi) {
            int pos = mi * 16 + l15;
            if (pos < 17) {
                float4 s4 = *(const float4*)(scl + pos * C_DIM + D0);
                float4 o4 = *(const float4*)(ofs + pos * C_DIM + D0);
                float4 g4 = *(const float4*)(gnv + pos * C_DIM + D0);
                float ss[4] = {s4.x, s4.y, s4.z, s4.w};
                float oo[4] = {o4.x, o4.y, o4.z, o4.w};
                float gi[4] = {g4.x, g4.y, g4.z, g4.w};
                // residual: 4 consecutive bf16 at As[pos][D0..D0+3]
                int hb = pos * 256 + ((((D0 >> 3) ^ (pos & 7)) << 3) | (D0 & 7));
                svec4 a4 = *(const svec4*)(As + hb);
                int vv = pos + dm; if (vv >= V) vv -= V;
                int base = n * CTV + D0 * TV + tr * V;
                #pragma unroll
                for (int rg = 0; rg < 4; ++rg) {
                    float x = bfs2f(a4[rg]) * gi[rg];
                    float val = acc[ni][mi][rg] * ss[rg] + oo[rg] + x;
                    out[base + rg * TV + vv] = fmaxf(val, 0.f);
                    if (++vv == V) vv = 0;
                }
            }
        }
    }
}

extern "C" void kernel_launch(void* const* d_in, const int* in_sizes, int n_in,
                              void* d_out, int out_size, void* d_ws, size_t ws_size,
                              hipStream_t stream)
{
    const float* x0    = (const float*)d_in[0];
    const float* fm    = (const float*)d_in[1];
    const float* W     = (const float*)d_in[2];
    const float* lb    = (const float*)d_in[3];
    const float* gamma = (const float*)d_in[4];
    const float* beta  = (const float*)d_in[5];
    const float* mean  = (const float*)d_in[6];
    const float* var   = (const float*)d_in[7];
    float* out = (float*)d_out;

    char* ws = (char*)d_ws;
    __hip_bfloat16* wtb = (__hip_bfloat16*)ws;
    float* g   = (float*)(ws + 131072);
    float* scl = (float*)(ws + 148480);
    float* ofs = (float*)(ws + 165888);
    float* gnv = (float*)(ws + 183296);

    prep_kernel<<<256, 256, 0, stream>>>(fm, W, lb, gamma, beta, mean, var,
                                         wtb, g, scl, ofs, gnv);
    shiftgcn_kernel<<<4096, 256, 0, stream>>>(x0, wtb, g, scl, ofs, gnv, out);
}

// Round 15
// 72.009 us; speedup vs baseline: 1.2866x; 1.2866x over previous
//
#include <hip/hip_runtime.h>
#include <hip/hip_bf16.h>

#define V 17
#define C_DIM 256
#define TV 1088        // T*V
#define CTV 278528     // C*T*V

typedef __attribute__((ext_vector_type(8))) short short8;
typedef __attribute__((ext_vector_type(4))) short svec4;
typedef __attribute__((ext_vector_type(4))) float f32x4;

static __device__ inline short f2bfs(float f) {
    union { __hip_bfloat16 b; short s; } u;
    u.b = __float2bfloat16(f);
    return u.s;
}
static __device__ inline float bfs2f(short s) {
    union { float f; unsigned u; } q;
    q.u = ((unsigned)(unsigned short)s) << 16;
    return q.f;
}

// ws layout (bytes):
//   0      : wtb (65536 bf16)  blocked W^T: wtb[(kc*256+d)*32+kk] = W[kc*32+kk][d]
//   131072 : g   (4352 f32)    tanh(fm)+1
//   148480 : scl (4352 f32)    [u][d] = gamma[v,d]/sqrt(var[v,d]+eps),  v=(u+d)%17
//   165888 : ofs (4352 f32)    [u][d] = (lin_b[d]-mean[v,d])*scl+beta[v,d]
//   183296 : gnv (4352 f32)    [u][d] = 1/g[u][d]
__global__ __launch_bounds__(256) void prep_kernel(
    const float* __restrict__ fm, const float* __restrict__ W,
    const float* __restrict__ lb, const float* __restrict__ gamma,
    const float* __restrict__ beta, const float* __restrict__ mean,
    const float* __restrict__ var,
    __hip_bfloat16* __restrict__ wtb, float* __restrict__ g,
    float* __restrict__ scl, float* __restrict__ ofs, float* __restrict__ gnv)
{
    int i = blockIdx.x * 256 + threadIdx.x;   // 65536 threads
    int c = i >> 8, d = i & 255;
    float w = W[i];
    wtb[((c >> 5) * 256 + d) * 32 + (c & 31)] = __float2bfloat16(w);
    if (i < V * C_DIM) {
        float gv = tanhf(fm[i]) + 1.0f;
        g[i]   = gv;
        gnv[i] = 1.0f / gv;
        int u = i >> 8;                        // GEMM-row joint
        int v = u + d; v %= V;                 // OUTPUT joint = (u+d) mod 17
        int k = v * C_DIM + d;                 // BN parameter index
        float sc = gamma[k] * rsqrtf(var[k] + 1e-5f);
        scl[i] = sc;
        ofs[i] = (lb[d] - mean[k]) * sc + beta[k];
    }
}

// ---- split staging: issue ALL loads first (deep MLP), convert+write later.
struct StageRegs { float xv[8]; float gg[8]; int waddr; };

static __device__ __forceinline__ void stage_load(
    int t, const float* __restrict__ xplane, const float* __restrict__ g,
    StageRegs& s)
{
    int kkc = t / 68;                  // 16B slot index
    int r   = t - kkc * 68;            // 0..67
    int tl  = r / 17;
    int u   = r - tl * 17;
    int c0  = kkc * 8;
    const float* gp = g + u * C_DIM + c0;
    float4 g0 = *(const float4*)gp;
    float4 g1 = *(const float4*)(gp + 4);
    s.gg[0]=g0.x; s.gg[1]=g0.y; s.gg[2]=g0.z; s.gg[3]=g0.w;
    s.gg[4]=g1.x; s.gg[5]=g1.y; s.gg[6]=g1.z; s.gg[7]=g1.w;
    const float* xb = xplane + tl * V;
    int mm = (u + c0) % V;
    #pragma unroll
    for (int i = 0; i < 8; ++i) {
        s.xv[i] = xb[(c0 + i) * TV + mm];
        mm = (mm == V - 1) ? 0 : mm + 1;
    }
    s.waddr = r * 256 + ((kkc ^ (r & 7)) << 3);
}

static __device__ __forceinline__ void stage_write(short* As, const StageRegs& s)
{
    short av[8];
    #pragma unroll
    for (int i = 0; i < 8; ++i) av[i] = f2bfs(s.xv[i] * s.gg[i]);
    *(short8*)(As + s.waddr) =
        (short8){av[0], av[1], av[2], av[3], av[4], av[5], av[6], av[7]};
}

// Block: 4 whole t-groups (68 GEMM rows, padded to 80), all 256 d.
// 512 thr / 8 waves. A-tile LDS: [80 rows][256 halves], XOR swizzle.
// MFMA with SWAPPED operands: lane col (l15) = GEMM row pos, output row
// (lq*4+rg) = d. Direct epilogue applies the output shift v=(pos%17+d)%17;
// residual x0[n,d,t,v] recovered from As[pos][d]*(1/g[u][d]).
// Staging: ALL gather loads issued before any convert/write (1 drain, not 5).
__global__ __launch_bounds__(512, 4) void shiftgcn_kernel(
    const float* __restrict__ x0, const __hip_bfloat16* __restrict__ wtb,
    const float* __restrict__ g, const float* __restrict__ scl,
    const float* __restrict__ ofs, const float* __restrict__ gnv,
    float* __restrict__ out)
{
    __shared__ __align__(16) short As[80 * 256];   // 40960 B

    const int tid  = threadIdx.x;
    const int lane = tid & 63;
    const int wv   = tid >> 6;                // 0..7
    const int l15  = lane & 15;
    const int lq   = lane >> 4;

    // T1: 1024 wg = 8 XCD x 128 contiguous tiles (bijective)
    const int wg  = (blockIdx.x & 7) * 128 + (blockIdx.x >> 3);
    const int nt0 = wg * 4;
    const int n   = nt0 >> 6;
    const int tb  = nt0 & 63;                 // multiple of 4
    const float* xplane = x0 + n * CTV + tb * V;   // + c*TV + tl*V + joint

    // zero pad rows 68..79 (12 rows * 256 halves = 384 short8)
    if (tid < 384) ((short8*)(As + 68 * 256))[tid] = (short8)0;

    // ---- Phase 1: stage all K. 2176 tasks; all loads in flight at once.
    StageRegs s0, s1, s2, s3, s4;
    const bool tail = tid < 128;
    stage_load(tid,        xplane, g, s0);
    stage_load(512  + tid, xplane, g, s1);
    stage_load(1024 + tid, xplane, g, s2);
    stage_load(1536 + tid, xplane, g, s3);
    if (tail) stage_load(2048 + tid, xplane, g, s4);
    stage_write(As, s0);
    stage_write(As, s1);
    stage_write(As, s2);
    stage_write(As, s3);
    if (tail) stage_write(As, s4);
    __syncthreads();   // the ONLY barrier

    // ---- Phase 2: MFMA, swapped operands. Wave wv owns d in [wv*32,wv*32+32).
    f32x4 acc[2][5];   // [dTile][posTile]
    #pragma unroll
    for (int ni = 0; ni < 2; ++ni)
        #pragma unroll
        for (int mi = 0; mi < 5; ++mi)
            acc[ni][mi] = (f32x4){0.f, 0.f, 0.f, 0.f};

    #pragma unroll
    for (int kc = 0; kc < 8; ++kc) {
        short8 wfr[2];
        #pragma unroll
        for (int ni = 0; ni < 2; ++ni)
            wfr[ni] = *(const short8*)(wtb +
                ((kc * 256 + wv * 32 + ni * 16 + l15) << 5) + lq * 8);
        #pragma unroll
        for (int mi = 0; mi < 5; ++mi) {
            int row = mi * 16 + l15;
            short8 a = *(const short8*)(As + row * 256 +
                ((((kc << 2) | lq) ^ (row & 7)) << 3));
            acc[0][mi] = __builtin_amdgcn_mfma_f32_16x16x32_bf16(wfr[0], a, acc[0][mi], 0, 0, 0);
            acc[1][mi] = __builtin_amdgcn_mfma_f32_16x16x32_bf16(wfr[1], a, acc[1][mi], 0, 0, 0);
        }
    }

    // ---- Phase 3: direct epilogue. Lane holds GEMM row pos = mi*16+l15
    //      (joint ur = pos%17), d = wv*32 + ni*16 + lq*4 + rg. Output joint
    //      vv = (ur + d) % 17. Tables indexed [ur][d] -> float4 loads.
    #pragma unroll
    for (int ni = 0; ni < 2; ++ni) {
        const int D0 = wv * 32 + ni * 16 + lq * 4;
        const int dm = D0 % V;
        int tl = 0, ur = l15;                 // pos = tl*17 + ur
        #pragma unroll
        for (int mi = 0; mi < 5; ++mi) {
            int pos = mi * 16 + l15;
            if (pos < 68) {
                float4 s4 = *(const float4*)(scl + ur * C_DIM + D0);
                float4 o4 = *(const float4*)(ofs + ur * C_DIM + D0);
                float4 g4 = *(const float4*)(gnv + ur * C_DIM + D0);
                float ss[4] = {s4.x, s4.y, s4.z, s4.w};
                float oo[4] = {o4.x, o4.y, o4.z, o4.w};
                float gi[4] = {g4.x, g4.y, g4.z, g4.w};
                // residual: 4 consecutive bf16 at As[pos][D0..D0+3]
                int hb = pos * 256 + ((((D0 >> 3) ^ (pos & 7)) << 3) | (D0 & 7));
                svec4 a4 = *(const svec4*)(As + hb);
                int vv = ur + dm; if (vv >= V) vv -= V;   // output joint, rg=0
                int base2 = n * CTV + D0 * TV + (tb + tl) * V;
                #pragma unroll
                for (int rg = 0; rg < 4; ++rg) {
                    float x = bfs2f(a4[rg]) * gi[rg];
                    float val = acc[ni][mi][rg] * ss[rg] + oo[rg] + x;
                    out[base2 + rg * TV + vv] = fmaxf(val, 0.f);
                    if (++vv == V) vv = 0;
                }
            }
            // pos += 16  =>  (ur==0) ? ur=16 : (ur-=1, tl+=1)
            if (ur == 0) ur = 16; else { ur -= 1; tl += 1; }
        }
    }
}

extern "C" void kernel_launch(void* const* d_in, const int* in_sizes, int n_in,
                              void* d_out, int out_size, void* d_ws, size_t ws_size,
                              hipStream_t stream)
{
    const float* x0    = (const float*)d_in[0];
    const float* fm    = (const float*)d_in[1];
    const float* W     = (const float*)d_in[2];
    const float* lb    = (const float*)d_in[3];
    const float* gamma = (const float*)d_in[4];
    const float* beta  = (const float*)d_in[5];
    const float* mean  = (const float*)d_in[6];
    const float* var   = (const float*)d_in[7];
    float* out = (float*)d_out;

    char* ws = (char*)d_ws;
    __hip_bfloat16* wtb = (__hip_bfloat16*)ws;
    float* g   = (float*)(ws + 131072);
    float* scl = (float*)(ws + 148480);
    float* ofs = (float*)(ws + 165888);
    float* gnv = (float*)(ws + 183296);

    prep_kernel<<<256, 256, 0, stream>>>(fm, W, lb, gamma, beta, mean, var,
                                         wtb, g, scl, ofs, gnv);
    shiftgcn_kernel<<<1024, 512, 0, stream>>>(x0, wtb, g, scl, ofs, gnv, out);
}

// Round 16
// 67.516 us; speedup vs baseline: 1.3722x; 1.0665x over previous
//
#include <hip/hip_runtime.h>
#include <hip/hip_bf16.h>

#define V 17
#define C_DIM 256
#define TV 1088        // T*V
#define CTV 278528     // C*T*V

typedef __attribute__((ext_vector_type(8))) short short8;
typedef __attribute__((ext_vector_type(4))) short svec4;
typedef __attribute__((ext_vector_type(4))) float f32x4;

static __device__ inline short f2bfs(float f) {
    union { __hip_bfloat16 b; short s; } u;
    u.b = __float2bfloat16(f);
    return u.s;
}
static __device__ inline float bfs2f(short s) {
    union { float f; unsigned u; } q;
    q.u = ((unsigned)(unsigned short)s) << 16;
    return q.f;
}

// ws layout (bytes):
//   0      : wtb (65536 bf16)  blocked W^T: wtb[(kc*256+d)*32+kk] = W[kc*32+kk][d]
//   131072 : g   (4352 f32)    tanh(fm)+1
//   148480 : scl (4352 f32)    [u][d] = gamma[v,d]/sqrt(var[v,d]+eps),  v=(u+d)%17
//   165888 : ofs (4352 f32)    [u][d] = (lin_b[d]-mean[v,d])*scl+beta[v,d]
//   183296 : gnv (4352 f32)    [u][d] = 1/g[u][d]
__global__ __launch_bounds__(256) void prep_kernel(
    const float* __restrict__ fm, const float* __restrict__ W,
    const float* __restrict__ lb, const float* __restrict__ gamma,
    const float* __restrict__ beta, const float* __restrict__ mean,
    const float* __restrict__ var,
    __hip_bfloat16* __restrict__ wtb, float* __restrict__ g,
    float* __restrict__ scl, float* __restrict__ ofs, float* __restrict__ gnv)
{
    int i = blockIdx.x * 256 + threadIdx.x;   // 65536 threads
    int c = i >> 8, d = i & 255;
    float w = W[i];
    wtb[((c >> 5) * 256 + d) * 32 + (c & 31)] = __float2bfloat16(w);
    if (i < V * C_DIM) {
        float gv = tanhf(fm[i]) + 1.0f;
        g[i]   = gv;
        gnv[i] = 1.0f / gv;
        int u = i >> 8;                        // GEMM-row joint
        int v = u + d; v %= V;                 // OUTPUT joint = (u+d) mod 17
        int k = v * C_DIM + d;                 // BN parameter index
        float sc = gamma[k] * rsqrtf(var[k] + 1e-5f);
        scl[i] = sc;
        ofs[i] = (lb[d] - mean[k]) * sc + beta[k];
    }
}

// ---- split staging: issue 2 tasks' loads, then convert+write (2-deep MLP).
struct StageRegs { float xv[8]; float gg[8]; int waddr; };

static __device__ __forceinline__ void stage_load(
    int t, const float* __restrict__ xplane, const float* __restrict__ g,
    StageRegs& s)
{
    int kkc = t / 68;                  // 16B slot index
    int r   = t - kkc * 68;            // 0..67
    int tl  = r / 17;
    int u   = r - tl * 17;
    int c0  = kkc * 8;
    const float* gp = g + u * C_DIM + c0;
    float4 g0 = *(const float4*)gp;
    float4 g1 = *(const float4*)(gp + 4);
    s.gg[0]=g0.x; s.gg[1]=g0.y; s.gg[2]=g0.z; s.gg[3]=g0.w;
    s.gg[4]=g1.x; s.gg[5]=g1.y; s.gg[6]=g1.z; s.gg[7]=g1.w;
    const float* xb = xplane + tl * V;
    int mm = (u + c0) % V;
    #pragma unroll
    for (int i = 0; i < 8; ++i) {
        s.xv[i] = xb[(c0 + i) * TV + mm];
        mm = (mm == V - 1) ? 0 : mm + 1;
    }
    s.waddr = r * 256 + ((kkc ^ (r & 7)) << 3);
}

static __device__ __forceinline__ void stage_write(short* As, const StageRegs& s)
{
    short av[8];
    #pragma unroll
    for (int i = 0; i < 8; ++i) av[i] = f2bfs(s.xv[i] * s.gg[i]);
    *(short8*)(As + s.waddr) =
        (short8){av[0], av[1], av[2], av[3], av[4], av[5], av[6], av[7]};
}

// Block: 4 whole t-groups (68 GEMM rows, padded to 80), all 256 d.
// 512 thr / 8 waves. A-tile LDS: [80 rows][256 halves], XOR swizzle.
// MFMA with SWAPPED operands: lane col (l15) = GEMM row pos, output row
// (lq*4+rg) = d. Direct epilogue applies output shift v=(pos%17+d)%17;
// residual x0[n,d,t,v] recovered from As[pos][d]*(1/g[u][d]).
// Latency plan: staging 2-deep (2 HBM drains, no spill); wtb fragments
// register-double-buffered across kc (kc0 prefetched before staging) so
// the per-kc L3 latency is never exposed.
__global__ __launch_bounds__(512, 4) void shiftgcn_kernel(
    const float* __restrict__ x0, const __hip_bfloat16* __restrict__ wtb,
    const float* __restrict__ g, const float* __restrict__ scl,
    const float* __restrict__ ofs, const float* __restrict__ gnv,
    float* __restrict__ out)
{
    __shared__ __align__(16) short As[80 * 256];   // 40960 B

    const int tid  = threadIdx.x;
    const int lane = tid & 63;
    const int wv   = tid >> 6;                // 0..7
    const int l15  = lane & 15;
    const int lq   = lane >> 4;

    // T1: 1024 wg = 8 XCD x 128 contiguous tiles (bijective)
    const int wg  = (blockIdx.x & 7) * 128 + (blockIdx.x >> 3);
    const int nt0 = wg * 4;
    const int n   = nt0 >> 6;
    const int tb  = nt0 & 63;                 // multiple of 4
    const float* xplane = x0 + n * CTV + tb * V;   // + c*TV + tl*V + joint

    // zero pad rows 68..79 (12 rows * 256 halves = 384 short8)
    if (tid < 384) ((short8*)(As + 68 * 256))[tid] = (short8)0;

    // wtb fragment base for this thread (elements): (ni,kc) -> + ni*512 + kc*8192
    const __hip_bfloat16* wbase = wtb + (((wv * 32 + l15) << 5) + lq * 8);

    // prefetch kc=0 fragments BEFORE staging: ready at P2 start
    short8 wc0 = *(const short8*)(wbase);
    short8 wc1 = *(const short8*)(wbase + 512);

    // ---- Phase 1: stage all K, 2-deep (2 drains + tail).
    StageRegs s0, s1;
    stage_load(tid,        xplane, g, s0);
    stage_load(512  + tid, xplane, g, s1);
    stage_write(As, s0);
    stage_write(As, s1);
    stage_load(1024 + tid, xplane, g, s0);
    stage_load(1536 + tid, xplane, g, s1);
    stage_write(As, s0);
    stage_write(As, s1);
    if (tid < 128) {
        stage_load(2048 + tid, xplane, g, s0);
        stage_write(As, s0);
    }
    __syncthreads();   // the ONLY barrier

    // ---- Phase 2: MFMA, swapped operands. Wave wv owns d in [wv*32,wv*32+32).
    //      wfr register-double-buffered across kc.
    f32x4 acc[2][5];   // [dTile][posTile]
    #pragma unroll
    for (int ni = 0; ni < 2; ++ni)
        #pragma unroll
        for (int mi = 0; mi < 5; ++mi)
            acc[ni][mi] = (f32x4){0.f, 0.f, 0.f, 0.f};

    #pragma unroll
    for (int kc = 0; kc < 8; ++kc) {
        short8 wn0, wn1;
        if (kc < 7) {
            wn0 = *(const short8*)(wbase + (kc + 1) * 8192);
            wn1 = *(const short8*)(wbase + (kc + 1) * 8192 + 512);
        }
        #pragma unroll
        for (int mi = 0; mi < 5; ++mi) {
            int row = mi * 16 + l15;
            short8 a = *(const short8*)(As + row * 256 +
                ((((kc << 2) | lq) ^ (row & 7)) << 3));
            acc[0][mi] = __builtin_amdgcn_mfma_f32_16x16x32_bf16(wc0, a, acc[0][mi], 0, 0, 0);
            acc[1][mi] = __builtin_amdgcn_mfma_f32_16x16x32_bf16(wc1, a, acc[1][mi], 0, 0, 0);
        }
        if (kc < 7) { wc0 = wn0; wc1 = wn1; }
    }

    // ---- Phase 3: direct epilogue. Lane holds GEMM row pos = mi*16+l15
    //      (joint ur = pos%17), d = wv*32 + ni*16 + lq*4 + rg. Output joint
    //      vv = (ur + d) % 17. Tables indexed [ur][d] -> float4 loads.
    #pragma unroll
    for (int ni = 0; ni < 2; ++ni) {
        const int D0 = wv * 32 + ni * 16 + lq * 4;
        const int dm = D0 % V;
        int tl = 0, ur = l15;                 // pos = tl*17 + ur
        #pragma unroll
        for (int mi = 0; mi < 5; ++mi) {
            int pos = mi * 16 + l15;
            if (pos < 68) {
                float4 s4 = *(const float4*)(scl + ur * C_DIM + D0);
                float4 o4 = *(const float4*)(ofs + ur * C_DIM + D0);
                float4 g4 = *(const float4*)(gnv + ur * C_DIM + D0);
                float ss[4] = {s4.x, s4.y, s4.z, s4.w};
                float oo[4] = {o4.x, o4.y, o4.z, o4.w};
                float gi[4] = {g4.x, g4.y, g4.z, g4.w};
                // residual: 4 consecutive bf16 at As[pos][D0..D0+3]
                int hb = pos * 256 + ((((D0 >> 3) ^ (pos & 7)) << 3) | (D0 & 7));
                svec4 a4 = *(const svec4*)(As + hb);
                int vv = ur + dm; if (vv >= V) vv -= V;   // output joint, rg=0
                int base2 = n * CTV + D0 * TV + (tb + tl) * V;
                #pragma unroll
                for (int rg = 0; rg < 4; ++rg) {
                    float x = bfs2f(a4[rg]) * gi[rg];
                    float val = acc[ni][mi][rg] * ss[rg] + oo[rg] + x;
                    out[base2 + rg * TV + vv] = fmaxf(val, 0.f);
                    if (++vv == V) vv = 0;
                }
            }
            // pos += 16  =>  (ur==0) ? ur=16 : (ur-=1, tl+=1)
            if (ur == 0) ur = 16; else { ur -= 1; tl += 1; }
        }
    }
}

extern "C" void kernel_launch(void* const* d_in, const int* in_sizes, int n_in,
                              void* d_out, int out_size, void* d_ws, size_t ws_size,
                              hipStream_t stream)
{
    const float* x0    = (const float*)d_in[0];
    const float* fm    = (const float*)d_in[1];
    const float* W     = (const float*)d_in[2];
    const float* lb    = (const float*)d_in[3];
    const float* gamma = (const float*)d_in[4];
    const float* beta  = (const float*)d_in[5];
    const float* mean  = (const float*)d_in[6];
    const float* var   = (const float*)d_in[7];
    float* out = (float*)d_out;

    char* ws = (char*)d_ws;
    __hip_bfloat16* wtb = (__hip_bfloat16*)ws;
    float* g   = (float*)(ws + 131072);
    float* scl = (float*)(ws + 148480);
    float* ofs = (float*)(ws + 165888);
    float* gnv = (float*)(ws + 183296);

    prep_kernel<<<256, 256, 0, stream>>>(fm, W, lb, gamma, beta, mean, var,
                                         wtb, g, scl, ofs, gnv);
    shiftgcn_kernel<<<1024, 512, 0, stream>>>(x0, wtb, g, scl, ofs, gnv, out);
}